// Round 1
// baseline (512.845 us; speedup 1.0000x reference)
//
#include <hip/hip_runtime.h>

// Attn_Pred_Model: 8-tap decayed shift-sum along S + biases, masked.
// x: [16,16,4096,64] fp32. Analytic mask/arange2 (no mask/arange2 reads),
// masked-strip skip, and — new this round — chunked register double-buffer:
// 8 independent row-loads in flight per wave (was a ~1-deep serial sliding
// window), loads grouped ahead of dependent stores in the vmcnt FIFO.
//
// Analytic identities (S=4096, BUCKET=64, BUCKETS_MIN=2):
//   arange2[s,j] = ((s>>6) - j) & 63
//   mask[s,j]    = (s >= 128) && (j < s>>6)
// q = s>>6 is strip-constant (strips are 32 rows, 32-aligned).

#define S_DIM 4096
#define PAST 8
#define RROWS 32                      // rows per thread
#define CHUNK 8                       // rows per load batch (= PAST)
#define STRIPS 16                     // strips per 256-thread block
#define BLOCK_ROWS (RROWS * STRIPS)   // 512 rows per block
#define BLOCKS_PER_PLANE (S_DIM / BLOCK_ROWS)  // 8

typedef float v4f __attribute__((ext_vector_type(4)));

// Compute+store CHUNK rows. W = previous 8 rows (window), C = this chunk's
// 8 rows. Row d of the chunk needs C[0..d-1] and W[d..7]; all indices are
// compile-time after unroll, so A/B stay in registers (no scratch).
#define DO_CHUNK(W, C, rbase)                                               \
    {                                                                       \
        _Pragma("unroll")                                                   \
        for (int d = 0; d < CHUNK; ++d) {                                   \
            v4f acc = c[0] * ((d - 1 >= 0) ? C[d - 1] : W[CHUNK + d - 1]);  \
            _Pragma("unroll")                                               \
            for (int i = 1; i < PAST; ++i) {                                \
                const int idx = d - 1 - i;                                  \
                acc += c[i] * ((idx >= 0) ? C[idx] : W[CHUNK + idx]);       \
            }                                                               \
            const v4f o = (acc + bias) * mk;                                \
            __builtin_nontemporal_store(o, &op[((rbase) + d) * 16 + j4]);   \
        }                                                                   \
    }

__global__ __launch_bounds__(256) void attn_pred_kernel(
    const float* __restrict__ x,
    const float* __restrict__ pb_fwd,
    const float* __restrict__ pb_bwd,
    const float* __restrict__ alpha_p,
    const float* __restrict__ beta_p,
    float* __restrict__ out)
{
    const int j4 = threadIdx.x & 15;          // which float4 along B
    const int st = threadIdx.x >> 4;          // strip within block
    const int bh = blockIdx.x >> 3;           // 8 blocks per [S,B] plane
    const int s0 = (blockIdx.x & 7) * BLOCK_ROWS + st * RROWS;
    const int q  = s0 >> 6;                   // strip-constant bucket row
    const int jb = j4 << 2;                   // first j of this thread's float4

    const size_t plane = (size_t)bh * (S_DIM * 16);   // in v4f units
    const v4f* __restrict__ xp = (const v4f*)x + plane;
    v4f* __restrict__       op = (v4f*)out + plane;

    // Fully-masked strip: write zeros, skip all loads.
    if (s0 < 128 || jb >= q) {
        const v4f z = (v4f){0.f, 0.f, 0.f, 0.f};
        #pragma unroll
        for (int r = 0; r < RROWS; ++r)
            __builtin_nontemporal_store(z, &op[(s0 + r) * 16 + j4]);
        return;
    }

    // s0 >= 128 here, so the window preload needs no s<0 guard.
    const float alpha = alpha_p[0];
    const float beta  = beta_p[0];
    float c[PAST];
    c[0] = alpha;
    #pragma unroll
    for (int i = 1; i < PAST; ++i) c[i] = c[i - 1] * beta;

    const v4f bf = ((const v4f*)pb_fwd)[j4];
    v4f bias;
    bias.x = bf.x + pb_bwd[(q - jb    ) & 63];
    bias.y = bf.y + pb_bwd[(q - jb - 1) & 63];
    bias.z = bf.z + pb_bwd[(q - jb - 2) & 63];
    bias.w = bf.w + pb_bwd[(q - jb - 3) & 63];

    v4f mk;
    mk.x = 1.f;                               // jb < q guaranteed here
    mk.y = (jb + 1 < q) ? 1.f : 0.f;
    mk.z = (jb + 2 < q) ? 1.f : 0.f;
    mk.w = (jb + 3 < q) ? 1.f : 0.f;

    // Register double-buffer: A/B alternate between "window" (previous 8
    // rows) and "current chunk" roles. 16 loads issued before the first
    // dependent use; 8-deep load pipeline in steady state.
    v4f A[CHUNK], B[CHUNK];

    #pragma unroll
    for (int k = 0; k < CHUNK; ++k)           // window: rows s0-8..s0-1
        A[k] = xp[(s0 - PAST + k) * 16 + j4];

    #pragma unroll
    for (int k = 0; k < CHUNK; ++k)           // chunk 0: rows s0..s0+7
        B[k] = xp[(s0 + k) * 16 + j4];
    DO_CHUNK(A, B, s0)

    #pragma unroll
    for (int k = 0; k < CHUNK; ++k)           // chunk 1
        A[k] = xp[(s0 + CHUNK + k) * 16 + j4];
    DO_CHUNK(B, A, s0 + CHUNK)

    #pragma unroll
    for (int k = 0; k < CHUNK; ++k)           // chunk 2
        B[k] = xp[(s0 + 2 * CHUNK + k) * 16 + j4];
    DO_CHUNK(A, B, s0 + 2 * CHUNK)

    #pragma unroll
    for (int k = 0; k < CHUNK; ++k)           // chunk 3
        A[k] = xp[(s0 + 3 * CHUNK + k) * 16 + j4];
    DO_CHUNK(B, A, s0 + 3 * CHUNK)
}

extern "C" void kernel_launch(void* const* d_in, const int* in_sizes, int n_in,
                              void* d_out, int out_size, void* d_ws, size_t ws_size,
                              hipStream_t stream) {
    const float* x       = (const float*)d_in[0];
    const float* pb_fwd  = (const float*)d_in[1];
    const float* pb_bwd  = (const float*)d_in[2];
    const float* alpha_p = (const float*)d_in[3];
    const float* beta_p  = (const float*)d_in[4];
    // d_in[5] = arange2 (int64), d_in[6] = mask -- both computed analytically
    float* out = (float*)d_out;

    const int grid = 16 * 16 * BLOCKS_PER_PLANE;  // 2048 blocks x 256 threads
    attn_pred_kernel<<<grid, 256, 0, stream>>>(x, pb_fwd, pb_bwd, alpha_p,
                                               beta_p, out);
}

// Round 2
// 498.393 us; speedup vs baseline: 1.0290x; 1.0290x over previous
//
#include <hip/hip_runtime.h>

// Attn_Pred_Model: 8-tap decayed shift-sum along S + biases, masked.
// x: [16,16,4096,64] fp32. Analytic mask/arange2 (no mask/arange2 reads),
// masked-strip skip, chunked register loads.
//
// Round 2 changes:
//  (a) blockIdx decode flipped: plane (bh) is fastest-varying, s_slot
//      slowest. With round-robin block->XCD dispatch, every XCD now sees
//      all 8 s-ranges and every CU gets one block of each weight
//      (was: s_slot == blockIdx%8 == XCD -> XCD7 got only the heaviest
//      strips, XCD0 only zeros; fully-resident grid has no backfill, so
//      the heavy XCD defined the runtime -> 36-71% time-avg occupancy).
//  (b) plain stores instead of __builtin_nontemporal_store: output is
//      write-once/never-read, nt bypass buys nothing, and the nt write
//      stream was pinned at ~1.37 TB/s across two schedules.
//
// Analytic identities (S=4096, BUCKET=64, BUCKETS_MIN=2):
//   arange2[s,j] = ((s>>6) - j) & 63
//   mask[s,j]    = (s >= 128) && (j < s>>6)
// q = s>>6 is strip-constant (strips are 32 rows, 32-aligned).

#define S_DIM 4096
#define PAST 8
#define RROWS 32                      // rows per thread
#define CHUNK 8                       // rows per load batch (= PAST)
#define STRIPS 16                     // strips per 256-thread block
#define BLOCK_ROWS (RROWS * STRIPS)   // 512 rows per block
#define BLOCKS_PER_PLANE (S_DIM / BLOCK_ROWS)  // 8
#define PLANES 256                    // 16*16

typedef float v4f __attribute__((ext_vector_type(4)));

// Compute+store CHUNK rows. W = previous 8 rows (window), C = this chunk's
// 8 rows. Row d of the chunk needs C[0..d-1] and W[d..7]; all indices are
// compile-time after unroll, so A/B stay in registers (no scratch).
#define DO_CHUNK(W, C, rbase)                                               \
    {                                                                       \
        _Pragma("unroll")                                                   \
        for (int d = 0; d < CHUNK; ++d) {                                   \
            v4f acc = c[0] * ((d - 1 >= 0) ? C[d - 1] : W[CHUNK + d - 1]);  \
            _Pragma("unroll")                                               \
            for (int i = 1; i < PAST; ++i) {                                \
                const int idx = d - 1 - i;                                  \
                acc += c[i] * ((idx >= 0) ? C[idx] : W[CHUNK + idx]);       \
            }                                                               \
            op[((rbase) + d) * 16 + j4] = (acc + bias) * mk;                \
        }                                                                   \
    }

__global__ __launch_bounds__(256) void attn_pred_kernel(
    const float* __restrict__ x,
    const float* __restrict__ pb_fwd,
    const float* __restrict__ pb_bwd,
    const float* __restrict__ alpha_p,
    const float* __restrict__ beta_p,
    float* __restrict__ out)
{
    const int j4 = threadIdx.x & 15;          // which float4 along B
    const int st = threadIdx.x >> 4;          // strip within block
    const int bh = blockIdx.x & (PLANES - 1); // plane: FASTEST-varying
    const int s_slot = blockIdx.x >> 8;       // s-range: slowest-varying
    const int s0 = s_slot * BLOCK_ROWS + st * RROWS;
    const int q  = s0 >> 6;                   // strip-constant bucket row
    const int jb = j4 << 2;                   // first j of this thread's float4

    const size_t plane = (size_t)bh * (S_DIM * 16);   // in v4f units
    const v4f* __restrict__ xp = (const v4f*)x + plane;
    v4f* __restrict__       op = (v4f*)out + plane;

    // Fully-masked strip: write zeros, skip all loads.
    if (s0 < 128 || jb >= q) {
        const v4f z = (v4f){0.f, 0.f, 0.f, 0.f};
        #pragma unroll
        for (int r = 0; r < RROWS; ++r)
            op[(s0 + r) * 16 + j4] = z;
        return;
    }

    // s0 >= 128 here, so the window preload needs no s<0 guard.
    const float alpha = alpha_p[0];
    const float beta  = beta_p[0];
    float c[PAST];
    c[0] = alpha;
    #pragma unroll
    for (int i = 1; i < PAST; ++i) c[i] = c[i - 1] * beta;

    const v4f bf = ((const v4f*)pb_fwd)[j4];
    v4f bias;
    bias.x = bf.x + pb_bwd[(q - jb    ) & 63];
    bias.y = bf.y + pb_bwd[(q - jb - 1) & 63];
    bias.z = bf.z + pb_bwd[(q - jb - 2) & 63];
    bias.w = bf.w + pb_bwd[(q - jb - 3) & 63];

    v4f mk;
    mk.x = 1.f;                               // jb < q guaranteed here
    mk.y = (jb + 1 < q) ? 1.f : 0.f;
    mk.z = (jb + 2 < q) ? 1.f : 0.f;
    mk.w = (jb + 3 < q) ? 1.f : 0.f;

    // Chunked loads: 8 independent row-loads issued back-to-back per batch.
    v4f A[CHUNK], B[CHUNK];

    #pragma unroll
    for (int k = 0; k < CHUNK; ++k)           // window: rows s0-8..s0-1
        A[k] = xp[(s0 - PAST + k) * 16 + j4];

    #pragma unroll
    for (int k = 0; k < CHUNK; ++k)           // chunk 0: rows s0..s0+7
        B[k] = xp[(s0 + k) * 16 + j4];
    DO_CHUNK(A, B, s0)

    #pragma unroll
    for (int k = 0; k < CHUNK; ++k)           // chunk 1
        A[k] = xp[(s0 + CHUNK + k) * 16 + j4];
    DO_CHUNK(B, A, s0 + CHUNK)

    #pragma unroll
    for (int k = 0; k < CHUNK; ++k)           // chunk 2
        B[k] = xp[(s0 + 2 * CHUNK + k) * 16 + j4];
    DO_CHUNK(A, B, s0 + 2 * CHUNK)

    #pragma unroll
    for (int k = 0; k < CHUNK; ++k)           // chunk 3
        A[k] = xp[(s0 + 3 * CHUNK + k) * 16 + j4];
    DO_CHUNK(B, A, s0 + 3 * CHUNK)
}

extern "C" void kernel_launch(void* const* d_in, const int* in_sizes, int n_in,
                              void* d_out, int out_size, void* d_ws, size_t ws_size,
                              hipStream_t stream) {
    const float* x       = (const float*)d_in[0];
    const float* pb_fwd  = (const float*)d_in[1];
    const float* pb_bwd  = (const float*)d_in[2];
    const float* alpha_p = (const float*)d_in[3];
    const float* beta_p  = (const float*)d_in[4];
    // d_in[5] = arange2 (int64), d_in[6] = mask -- both computed analytically
    float* out = (float*)d_out;

    const int grid = PLANES * BLOCKS_PER_PLANE;  // 2048 blocks x 256 threads
    attn_pred_kernel<<<grid, 256, 0, stream>>>(x, pb_fwd, pb_bwd, alpha_p,
                                               beta_p, out);
}